// Round 6
// baseline (397.037 us; speedup 1.0000x reference)
//
#include <hip/hip_runtime.h>

#define NROWS 65536
#define KDIM  512
constexpr float BN_EPS = 1e-5f;

using short8 = __attribute__((ext_vector_type(8))) short;
using f32x4  = __attribute__((ext_vector_type(4))) float;

#define BM 64

// Split fp32 -> bf16 hi (truncate) + bf16 lo (truncated remainder).
__device__ __forceinline__ void cvt8(const float4& a, const float4& b, short8& hi, short8& lo) {
  const float e[8] = {a.x, a.y, a.z, a.w, b.x, b.y, b.z, b.w};
  #pragma unroll
  for (int i = 0; i < 8; ++i) {
    const unsigned u = __float_as_uint(e[i]);
    const float r = e[i] - __uint_as_float(u & 0xFFFF0000u);
    hi[i] = (short)(u >> 16);
    lo[i] = (short)(__float_as_uint(r) >> 16);
  }
}

// ---------------- prep: C1 -> fragment-tiled bf16 hi/lo ----------------
// c1t entry e = kg*512 + col (kg = global k-group 0..63) holds 8 shorts:
// C1[kg*8 + i][col], i = 0..7. A lane's B-fragment is ONE contiguous entry.
__global__ __launch_bounds__(256)
void prep_c1(const float* __restrict__ C1, short8* __restrict__ c1tH,
             short8* __restrict__ c1tL) {
  const int e   = blockIdx.x * 256 + threadIdx.x;   // 0..32767
  const int col = e & 511;
  const int kg  = e >> 9;
  short8 hi, lo;
  #pragma unroll
  for (int i = 0; i < 8; ++i) {
    const float x = C1[(size_t)(kg * 8 + i) * KDIM + col];   // coalesced across lanes
    const unsigned u = __float_as_uint(x);
    const float r = x - __uint_as_float(u & 0xFFFF0000u);
    hi[i] = (short)(u >> 16);
    lo[i] = (short)(__float_as_uint(r) >> 16);
  }
  c1tH[e] = hi;
  c1tL[e] = lo;
}

// ---------------- quad: zero-barrier register-direct MFMA ----------------
// quad[n] = x_n^T C1 x_n  (split-bf16, 3 MFMA passes: HH + LH + HL),
// fused with column-stat partials. BM=64 -> 1024 blocks -> 4 blocks/CU
// (4 waves/SIMD) for latency hiding; launch_bounds caps VGPR at 128.
__global__ __launch_bounds__(256, 4)
void quad_kernel(const float* __restrict__ X,
                 const short8* __restrict__ c1tH, const short8* __restrict__ c1tL,
                 float* __restrict__ quad,
                 float* __restrict__ colS1, float* __restrict__ colS2,
                 float* __restrict__ colS3, double* __restrict__ qsums) {
  __shared__ float qPart[2][BM];
  __shared__ float qLds[BM];

  const int tid  = threadIdx.x;
  const int lane = tid & 63;
  const int wid  = tid >> 6;
  const int wm   = wid >> 1;          // wave row-half (0..1): 32 rows each
  const int wj   = wid & 1;           // wave col-half (0..1): 64 cols each
  const int g    = lane >> 4;         // k-group 0..3
  const int lr   = lane & 15;
  const int r0   = blockIdx.x * BM;

  const float* xbase = X + (size_t)(r0 + wm * 32 + lr) * KDIM;  // + rf*16*KDIM + koff

  float qacc[8] = {};                 // [rf*4 + p] row partials (this wave's wj half)

  for (int jt = 0; jt < 4; ++jt) {
    const int j0 = jt * 128;
    f32x4 acc[2][4];
    #pragma unroll
    for (int rf = 0; rf < 2; ++rf)
      #pragma unroll
      for (int cf = 0; cf < 4; ++cf)
        acc[rf][cf] = (f32x4){0.f, 0.f, 0.f, 0.f};

    for (int kt = 0; kt < 16; ++kt) {
      // B fragments: direct from pre-tiled global (L2-resident), 16B/lane
      const int eb = (kt * 4 + g) * KDIM + j0 + wj * 64 + lr;
      short8 bH[4], bL[4];
      #pragma unroll
      for (int cf = 0; cf < 4; ++cf) {
        bH[cf] = c1tH[eb + cf * 16];
        bL[cf] = c1tL[eb + cf * 16];
      }
      // A raw: 32B per lane, rows wm*32+rf*16+lr, k-slice kt*32+g*8
      float4 xr0[2], xr1[2];
      #pragma unroll
      for (int rf = 0; rf < 2; ++rf) {
        const float* xp = xbase + rf * (16 * KDIM) + kt * 32 + g * 8;
        xr0[rf] = *(const float4*)xp;
        xr1[rf] = *(const float4*)(xp + 4);
      }
      #pragma unroll
      for (int rf = 0; rf < 2; ++rf) {
        short8 aH, aL;
        cvt8(xr0[rf], xr1[rf], aH, aL);
        #pragma unroll
        for (int cf = 0; cf < 4; ++cf) {
          acc[rf][cf] = __builtin_amdgcn_mfma_f32_16x16x32_bf16(aH, bH[cf], acc[rf][cf], 0, 0, 0);
          acc[rf][cf] = __builtin_amdgcn_mfma_f32_16x16x32_bf16(aL, bH[cf], acc[rf][cf], 0, 0, 0);
          acc[rf][cf] = __builtin_amdgcn_mfma_f32_16x16x32_bf16(aH, bL[cf], acc[rf][cf], 0, 0, 0);
        }
      }
    }
    // epilogue: qacc += Y[row, j] * X[row, j] for this wave's wj half
    #pragma unroll
    for (int rf = 0; rf < 2; ++rf)
      #pragma unroll
      for (int p = 0; p < 4; ++p) {
        const int grow = r0 + wm * 32 + rf * 16 + g * 4 + p;
        const float* xr = X + (size_t)grow * KDIM + j0 + wj * 64;
        float s = 0.f;
        #pragma unroll
        for (int cf = 0; cf < 4; ++cf)
          s += acc[rf][cf][p] * xr[cf * 16 + lr];
        qacc[rf * 4 + p] += s;
      }
  }

  // reduce across the 16 lanes of each lane-group; stash per-wj partials
  #pragma unroll
  for (int s = 0; s < 8; ++s) {
    float q = qacc[s];
    q += __shfl_xor(q, 1, 64);
    q += __shfl_xor(q, 2, 64);
    q += __shfl_xor(q, 4, 64);
    q += __shfl_xor(q, 8, 64);
    if (lr == 0) {
      const int row = wm * 32 + (s >> 2) * 16 + g * 4 + (s & 3);
      qPart[wj][row] = q;
    }
  }
  __syncthreads();
  if (tid < BM) {
    const float q = qPart[0][tid] + qPart[1][tid];
    quad[r0 + tid] = q;
    qLds[tid] = q;
  }
  __syncthreads();
  // fused column stats over the (cache-hot) X panel
  {
    float s1a = 0.f, s2a = 0.f, s3a = 0.f, s1b = 0.f, s2b = 0.f, s3b = 0.f;
    for (int r = 0; r < BM; ++r) {
      const float q = qLds[r];
      const float* xp = X + (size_t)(r0 + r) * KDIM + tid;
      const float x0 = xp[0];
      const float x1 = xp[256];
      s1a += x0; s2a += x0 * x0; s3a += q * x0;
      s1b += x1; s2b += x1 * x1; s3b += q * x1;
    }
    atomicAdd(&colS1[tid], s1a); atomicAdd(&colS1[tid + 256], s1b);
    atomicAdd(&colS2[tid], s2a); atomicAdd(&colS2[tid + 256], s2b);
    atomicAdd(&colS3[tid], s3a); atomicAdd(&colS3[tid + 256], s3b);
  }
  if (tid < BM) {   // one full wave (BM==64): reduce q, q^2 across 64 lanes
    double q = (double)qLds[tid];
    double q2 = q * q;
    #pragma unroll
    for (int m = 1; m < 64; m <<= 1) {
      q  += __shfl_xor(q,  m, 64);
      q2 += __shfl_xor(q2, m, 64);
    }
    if (tid == 0) { atomicAdd(&qsums[0], q); atomicAdd(&qsums[1], q2); }
  }
}

// ---------------- finalize per-feature mean / inv_std ----------------
__global__ void finalize_kernel(const float* __restrict__ colS1, const float* __restrict__ colS2,
                                const float* __restrict__ colS3, const double* __restrict__ qsums,
                                const float* __restrict__ C2, const float* __restrict__ C3,
                                float* __restrict__ mean, float* __restrict__ inv_std) {
  const int k = blockIdx.x * blockDim.x + threadIdx.x;
  if (k >= KDIM) return;
  const double invN = 1.0 / (double)NROWS;
  const double meanQ = qsums[0] * invN;
  const double varQ  = qsums[1] * invN - meanQ * meanQ;
  const float meanX = colS1[k] * (float)invN;
  const float varX  = colS2[k] * (float)invN - meanX * meanX;
  const float covQX = colS3[k] * (float)invN - (float)meanQ * meanX;
  const float c2 = C2[k];
  const float c3 = C3[0];
  const float m = (float)meanQ + c2 * meanX + c3;
  const float v = (float)varQ + c2 * c2 * varX + 2.0f * c2 * covQX;
  mean[k] = m;
  inv_std[k] = 1.0f / sqrtf(v + BN_EPS);
}

// ---------------- normalize + write ----------------
__global__ __launch_bounds__(256)
void normalize_kernel(const float* __restrict__ X, const float* __restrict__ quad,
                      const float* __restrict__ C2, const float* __restrict__ C3,
                      const float* __restrict__ mean, const float* __restrict__ inv_std,
                      float* __restrict__ out) {
  const int idx = blockIdx.x * blockDim.x + threadIdx.x;  // float4 index
  const int n = idx >> 7;
  const int j4 = idx & 127;
  const float q = quad[n];
  const float c3 = C3[0];
  const float4 x  = *(const float4*)&X[(size_t)idx * 4];
  const float4 c2 = *(const float4*)&C2[j4 * 4];
  const float4 m  = *(const float4*)&mean[j4 * 4];
  const float4 iv = *(const float4*)&inv_std[j4 * 4];
  float4 o;
  o.x = (q + c2.x * x.x + c3 - m.x) * iv.x;
  o.y = (q + c2.y * x.y + c3 - m.y) * iv.y;
  o.z = (q + c2.z * x.z + c3 - m.z) * iv.z;
  o.w = (q + c2.w * x.w + c3 - m.w) * iv.w;
  *(float4*)&out[(size_t)idx * 4] = o;
}

extern "C" void kernel_launch(void* const* d_in, const int* in_sizes, int n_in,
                              void* d_out, int out_size, void* d_ws, size_t ws_size,
                              hipStream_t stream) {
  const float* X  = (const float*)d_in[0];
  const float* C1 = (const float*)d_in[1];
  const float* C2 = (const float*)d_in[2];
  const float* C3 = (const float*)d_in[3];
  float* out = (float*)d_out;

  char* ws = (char*)d_ws;
  float*  quad    = (float*)ws;                                        // 256 KB
  float*  colS1   = (float*)(ws + (size_t)NROWS * 4);                  // K
  float*  colS2   = colS1 + KDIM;
  float*  colS3   = colS2 + KDIM;
  double* qsums   = (double*)(ws + (size_t)NROWS * 4 + 3 * KDIM * 4);  // 2 doubles
  float*  mean    = (float*)(ws + (size_t)NROWS * 4 + 3 * KDIM * 4 + 16);
  float*  inv_std = mean + KDIM;
  short8* c1tH    = (short8*)(ws + 276480);                            // 512 KB (16B aligned)
  short8* c1tL    = (short8*)(ws + 276480 + 524288);                   // 512 KB

  hipMemsetAsync(colS1, 0, 3 * KDIM * 4 + 16, stream);

  prep_c1<<<128, 256, 0, stream>>>(C1, c1tH, c1tL);
  quad_kernel<<<NROWS / BM, 256, 0, stream>>>(X, c1tH, c1tL, quad,
                                              colS1, colS2, colS3, qsums);
  finalize_kernel<<<2, 256, 0, stream>>>(colS1, colS2, colS3, qsums, C2, C3, mean, inv_std);
  normalize_kernel<<<(NROWS * (KDIM / 4)) / 256, 256, 0, stream>>>(
      X, quad, C2, C3, mean, inv_std, out);
}

// Round 7
// 225.232 us; speedup vs baseline: 1.7628x; 1.7628x over previous
//
#include <hip/hip_runtime.h>

#define NROWS 65536
#define KDIM  512
constexpr float BN_EPS = 1e-5f;

using short8 = __attribute__((ext_vector_type(8))) short;
using f32x4  = __attribute__((ext_vector_type(4))) float;

#define BM 128

// async global->LDS, 16B per lane (m97 pattern)
__device__ __forceinline__ void gload_lds16(const float* g, float* l) {
  __builtin_amdgcn_global_load_lds(
      (const __attribute__((address_space(1))) void*)g,
      (__attribute__((address_space(3))) void*)l, 16, 0, 0);
}

// RNE fp32 -> bf16 pack of 8 floats
__device__ __forceinline__ short8 cvthi8(const float4& a, const float4& b) {
  const float e[8] = {a.x, a.y, a.z, a.w, b.x, b.y, b.z, b.w};
  short8 h;
  #pragma unroll
  for (int i = 0; i < 8; ++i) {
    unsigned u = __float_as_uint(e[i]);
    u += 0x7FFFu + ((u >> 16) & 1u);
    h[i] = (short)(u >> 16);
  }
  return h;
}

// ---------------- prep: C1 -> fragment-tiled bf16 (RNE) ----------------
// entry e = kg*512 + col holds C1[kg*8 + i][col], i=0..7 (one B-fragment).
__global__ __launch_bounds__(256)
void prep_c1(const float* __restrict__ C1, short8* __restrict__ c1tH) {
  const int e   = blockIdx.x * 256 + threadIdx.x;   // 0..32767
  const int col = e & 511;
  const int kg  = e >> 9;
  short8 hi;
  #pragma unroll
  for (int i = 0; i < 8; ++i) {
    const float x = C1[(size_t)(kg * 8 + i) * KDIM + col];   // coalesced
    unsigned u = __float_as_uint(x);
    u += 0x7FFFu + ((u >> 16) & 1u);
    hi[i] = (short)(u >> 16);
  }
  c1tH[e] = hi;
}

// ---------------- quad: LDS-staged (global_load_lds, dbuf) 1-pass bf16 MFMA ----------------
// quad[n] = x_n^T C1 x_n; fused column stats.
// A tile (128 rows x 32 k, fp32) staged async into LDS, swizzled at the
// SOURCE (chunk kc stored at slot kc ^ (row&7)) so ds_read_b128 fragment
// reads are bank-conflict-minimal while global_load_lds dest stays linear.
// A is jt-invariant: wrap prefetch (kt+1)&15 keeps the pipeline primed
// across jt boundaries. One __syncthreads per kt.
__global__ __launch_bounds__(256)
void quad_kernel(const float* __restrict__ X, const short8* __restrict__ c1tH,
                 float* __restrict__ quad,
                 float* __restrict__ colS1, float* __restrict__ colS2,
                 float* __restrict__ colS3, double* __restrict__ qsums) {
  __shared__ float As[2][BM * 32];    // 2 x 16 KB, fp32, chunk-swizzled
  __shared__ float qPart[2][BM];
  __shared__ float qLds[BM];

  const int tid  = threadIdx.x;
  const int lane = tid & 63;
  const int wid  = tid >> 6;
  const int wm   = wid >> 1;          // wave row-half (0..1)
  const int wj   = wid & 1;           // wave col-half (0..1)
  const int g    = lane >> 4;         // k-group 0..3
  const int lr   = lane & 15;
  const int r0   = blockIdx.x * BM;

#define STAGE(buf, kt)                                                    \
  {                                                                       \
    _Pragma("unroll")                                                     \
    for (int w = 0; w < 4; ++w) {                                         \
      const int f = w * 256 + tid;                                        \
      const int row = f >> 3;                                             \
      const int c = f & 7;                                                \
      gload_lds16(X + (size_t)(r0 + row) * KDIM + (kt) * 32 +             \
                      ((c ^ (row & 7)) * 4),                              \
                  &As[buf][f * 4]);                                       \
    }                                                                     \
  }

  float qacc[16] = {};                // [rf*4 + p] row partials (this wj half)

  STAGE(0, 0);                        // prologue
  __syncthreads();
  int cur = 0;

  for (int jt = 0; jt < 4; ++jt) {
    const int j0 = jt * 128;
    f32x4 acc[4][4];
    #pragma unroll
    for (int rf = 0; rf < 4; ++rf)
      #pragma unroll
      for (int cf = 0; cf < 4; ++cf)
        acc[rf][cf] = (f32x4){0.f, 0.f, 0.f, 0.f};

    for (int kt = 0; kt < 16; ++kt) {
      // B fragments from pre-tiled L2-resident c1tH (issued first so the
      // compiler's waits for B don't force the stage loads to drain)
      const int eb = (kt * 4 + g) * KDIM + j0 + wj * 64 + lr;
      short8 bH[4];
      #pragma unroll
      for (int cf = 0; cf < 4; ++cf) bH[cf] = c1tH[eb + cf * 16];

      // async-prefetch next A tile (jt-invariant -> wrap at 16)
      STAGE(cur ^ 1, (kt + 1) & 15);

      // A fragments from LDS (swizzled chunks), cvt to bf16, MFMA
      #pragma unroll
      for (int rf = 0; rf < 4; ++rf) {
        const int row = wm * 64 + rf * 16 + lr;
        const int base = row * 32;
        const float4 a0 = *(const float4*)&As[cur][base + (((2 * g) ^ (row & 7)) * 4)];
        const float4 a1 = *(const float4*)&As[cur][base + (((2 * g + 1) ^ (row & 7)) * 4)];
        const short8 aH = cvthi8(a0, a1);
        #pragma unroll
        for (int cf = 0; cf < 4; ++cf)
          acc[rf][cf] = __builtin_amdgcn_mfma_f32_16x16x32_bf16(aH, bH[cf], acc[rf][cf], 0, 0, 0);
      }
      __syncthreads();
      cur ^= 1;
    }
    // epilogue: qacc += Y[row, j] * X[row, j] for this wave's wj half
    #pragma unroll
    for (int rf = 0; rf < 4; ++rf)
      #pragma unroll
      for (int p = 0; p < 4; ++p) {
        const int grow = r0 + wm * 64 + rf * 16 + g * 4 + p;
        const float* xr = X + (size_t)grow * KDIM + j0 + wj * 64;
        float s = 0.f;
        #pragma unroll
        for (int cf = 0; cf < 4; ++cf)
          s += acc[rf][cf][p] * xr[cf * 16 + lr];
        qacc[rf * 4 + p] += s;
      }
  }
#undef STAGE

  // reduce across the 16 lanes of each lane-group; stash per-wj partials
  #pragma unroll
  for (int s = 0; s < 16; ++s) {
    float q = qacc[s];
    q += __shfl_xor(q, 1, 64);
    q += __shfl_xor(q, 2, 64);
    q += __shfl_xor(q, 4, 64);
    q += __shfl_xor(q, 8, 64);
    if (lr == 0) {
      const int row = wm * 64 + (s >> 2) * 16 + g * 4 + (s & 3);
      qPart[wj][row] = q;
    }
  }
  __syncthreads();
  if (tid < BM) {
    const float q = qPart[0][tid] + qPart[1][tid];
    quad[r0 + tid] = q;
    qLds[tid] = q;
  }
  __syncthreads();
  // fused column stats over the (cache-hot) X panel
  {
    float s1a = 0.f, s2a = 0.f, s3a = 0.f, s1b = 0.f, s2b = 0.f, s3b = 0.f;
    for (int r = 0; r < BM; ++r) {
      const float q = qLds[r];
      const float* xp = X + (size_t)(r0 + r) * KDIM + tid;
      const float x0 = xp[0];
      const float x1 = xp[256];
      s1a += x0; s2a += x0 * x0; s3a += q * x0;
      s1b += x1; s2b += x1 * x1; s3b += q * x1;
    }
    atomicAdd(&colS1[tid], s1a); atomicAdd(&colS1[tid + 256], s1b);
    atomicAdd(&colS2[tid], s2a); atomicAdd(&colS2[tid + 256], s2b);
    atomicAdd(&colS3[tid], s3a); atomicAdd(&colS3[tid + 256], s3b);
  }
  if (tid < BM) {
    double q = (double)qLds[tid];
    double q2 = q * q;
    #pragma unroll
    for (int m = 1; m < 64; m <<= 1) {
      q  += __shfl_xor(q,  m, 64);
      q2 += __shfl_xor(q2, m, 64);
    }
    if ((tid & 63) == 0) { atomicAdd(&qsums[0], q); atomicAdd(&qsums[1], q2); }
  }
}

// ---------------- finalize per-feature mean / inv_std ----------------
__global__ void finalize_kernel(const float* __restrict__ colS1, const float* __restrict__ colS2,
                                const float* __restrict__ colS3, const double* __restrict__ qsums,
                                const float* __restrict__ C2, const float* __restrict__ C3,
                                float* __restrict__ mean, float* __restrict__ inv_std) {
  const int k = blockIdx.x * blockDim.x + threadIdx.x;
  if (k >= KDIM) return;
  const double invN = 1.0 / (double)NROWS;
  const double meanQ = qsums[0] * invN;
  const double varQ  = qsums[1] * invN - meanQ * meanQ;
  const float meanX = colS1[k] * (float)invN;
  const float varX  = colS2[k] * (float)invN - meanX * meanX;
  const float covQX = colS3[k] * (float)invN - (float)meanQ * meanX;
  const float c2 = C2[k];
  const float c3 = C3[0];
  const float m = (float)meanQ + c2 * meanX + c3;
  const float v = (float)varQ + c2 * c2 * varX + 2.0f * c2 * covQX;
  mean[k] = m;
  inv_std[k] = 1.0f / sqrtf(v + BN_EPS);
}

// ---------------- normalize + write ----------------
__global__ __launch_bounds__(256)
void normalize_kernel(const float* __restrict__ X, const float* __restrict__ quad,
                      const float* __restrict__ C2, const float* __restrict__ C3,
                      const float* __restrict__ mean, const float* __restrict__ inv_std,
                      float* __restrict__ out) {
  const int idx = blockIdx.x * blockDim.x + threadIdx.x;  // float4 index
  const int n = idx >> 7;
  const int j4 = idx & 127;
  const float q = quad[n];
  const float c3 = C3[0];
  const float4 x  = *(const float4*)&X[(size_t)idx * 4];
  const float4 c2 = *(const float4*)&C2[j4 * 4];
  const float4 m  = *(const float4*)&mean[j4 * 4];
  const float4 iv = *(const float4*)&inv_std[j4 * 4];
  float4 o;
  o.x = (q + c2.x * x.x + c3 - m.x) * iv.x;
  o.y = (q + c2.y * x.y + c3 - m.y) * iv.y;
  o.z = (q + c2.z * x.z + c3 - m.z) * iv.z;
  o.w = (q + c2.w * x.w + c3 - m.w) * iv.w;
  *(float4*)&out[(size_t)idx * 4] = o;
}

extern "C" void kernel_launch(void* const* d_in, const int* in_sizes, int n_in,
                              void* d_out, int out_size, void* d_ws, size_t ws_size,
                              hipStream_t stream) {
  const float* X  = (const float*)d_in[0];
  const float* C1 = (const float*)d_in[1];
  const float* C2 = (const float*)d_in[2];
  const float* C3 = (const float*)d_in[3];
  float* out = (float*)d_out;

  char* ws = (char*)d_ws;
  float*  quad    = (float*)ws;                                        // 256 KB
  float*  colS1   = (float*)(ws + (size_t)NROWS * 4);                  // K
  float*  colS2   = colS1 + KDIM;
  float*  colS3   = colS2 + KDIM;
  double* qsums   = (double*)(ws + (size_t)NROWS * 4 + 3 * KDIM * 4);  // 2 doubles
  float*  mean    = (float*)(ws + (size_t)NROWS * 4 + 3 * KDIM * 4 + 16);
  float*  inv_std = mean + KDIM;
  short8* c1tH    = (short8*)(ws + 276480);                            // 512 KB (16B aligned)

  hipMemsetAsync(colS1, 0, 3 * KDIM * 4 + 16, stream);

  prep_c1<<<128, 256, 0, stream>>>(C1, c1tH);
  quad_kernel<<<NROWS / BM, 256, 0, stream>>>(X, c1tH, quad,
                                              colS1, colS2, colS3, qsums);
  finalize_kernel<<<2, 256, 0, stream>>>(colS1, colS2, colS3, qsums, C2, C3, mean, inv_std);
  normalize_kernel<<<(NROWS * (KDIM / 4)) / 256, 256, 0, stream>>>(
      X, quad, C2, C3, mean, inv_std, out);
}

// Round 8
// 163.731 us; speedup vs baseline: 2.4249x; 1.3756x over previous
//
#include <hip/hip_runtime.h>

#define NROWS 65536
#define KDIM  512
constexpr float BN_EPS = 1e-5f;

using short8 = __attribute__((ext_vector_type(8))) short;
using f32x4  = __attribute__((ext_vector_type(4))) float;

#define BM 64

// RNE fp32 -> bf16 pack of 8 floats
__device__ __forceinline__ short8 cvthi8(const float4& a, const float4& b) {
  const float e[8] = {a.x, a.y, a.z, a.w, b.x, b.y, b.z, b.w};
  short8 h;
  #pragma unroll
  for (int i = 0; i < 8; ++i) {
    unsigned u = __float_as_uint(e[i]);
    u += 0x7FFFu + ((u >> 16) & 1u);
    h[i] = (short)(u >> 16);
  }
  return h;
}

// ---------------- prep: C1 -> fragment-tiled bf16 (RNE) ----------------
// entry e = kg*512 + col holds C1[kg*8 + i][col], i=0..7 (one B-fragment
// for lane (g=kg%4, lr=col%16) at k-tile kg/4).
__global__ __launch_bounds__(256)
void prep_c1(const float* __restrict__ C1, short8* __restrict__ c1tH) {
  const int e   = blockIdx.x * 256 + threadIdx.x;   // 0..32767
  const int col = e & 511;
  const int kg  = e >> 9;
  short8 hi;
  #pragma unroll
  for (int i = 0; i < 8; ++i) {
    const float x = C1[(size_t)(kg * 8 + i) * KDIM + col];   // coalesced
    unsigned u = __float_as_uint(x);
    u += 0x7FFFu + ((u >> 16) & 1u);
    hi[i] = (short)(u >> 16);
  }
  c1tH[e] = hi;
}

// ---------------- quad: register-resident A, zero-barrier, zero-LDS main loop ----------------
// quad[n] = x_n^T C1 x_n (1-pass bf16 MFMA), fused column stats.
// Each of 4 waves owns 16 rows; its A operand (16 x 512 bf16 = 64 VGPR)
// is loaded from HBM ONCE and converted in-register. The jt/kt loop then
// reads only B fragments from the pre-tiled L2-resident c1t (shared by
// all waves -> L1 hits). No LDS, no __syncthreads until the tail.
__global__ __launch_bounds__(256)
void quad_kernel(const float* __restrict__ X, const short8* __restrict__ c1tH,
                 float* __restrict__ quad,
                 float* __restrict__ colS1, float* __restrict__ colS2,
                 float* __restrict__ colS3, double* __restrict__ qsums) {
  __shared__ float qLds[BM];

  const int tid  = threadIdx.x;
  const int lane = tid & 63;
  const int w    = tid >> 6;          // wave 0..3 -> rows w*16..w*16+15
  const int g    = lane >> 4;         // k-group 0..3
  const int lr   = lane & 15;
  const int r0   = blockIdx.x * BM;

  // ---- one-time A load: lane (g,lr) holds X[r0+w*16+lr][kt*32+g*8 .. +7] ----
  short8 A[16];
  {
    const float* xp = X + (size_t)(r0 + w * 16 + lr) * KDIM + g * 8;
    #pragma unroll
    for (int kt = 0; kt < 16; ++kt) {
      const float4 a0 = *(const float4*)(xp + kt * 32);
      const float4 a1 = *(const float4*)(xp + kt * 32 + 4);
      A[kt] = cvthi8(a0, a1);
    }
  }

  float qacc[4] = {};                 // per-lane row partials (rows g*4+p)

  for (int jt = 0; jt < 8; ++jt) {    // 8 j-tiles of 64 cols
    const int j0 = jt * 64;
    f32x4 acc[4];
    #pragma unroll
    for (int cf = 0; cf < 4; ++cf) acc[cf] = (f32x4){0.f, 0.f, 0.f, 0.f};

    #pragma unroll
    for (int kt = 0; kt < 16; ++kt) {
      const int eb = (kt * 4 + g) * KDIM + j0 + lr;
      acc[0] = __builtin_amdgcn_mfma_f32_16x16x32_bf16(A[kt], c1tH[eb],      acc[0], 0, 0, 0);
      acc[1] = __builtin_amdgcn_mfma_f32_16x16x32_bf16(A[kt], c1tH[eb + 16], acc[1], 0, 0, 0);
      acc[2] = __builtin_amdgcn_mfma_f32_16x16x32_bf16(A[kt], c1tH[eb + 32], acc[2], 0, 0, 0);
      acc[3] = __builtin_amdgcn_mfma_f32_16x16x32_bf16(A[kt], c1tH[eb + 48], acc[3], 0, 0, 0);
    }
    // epilogue: qacc[p] += Y[row, j] * X[row, j], row = g*4+p, cols j0..j0+63
    #pragma unroll
    for (int p = 0; p < 4; ++p) {
      const float* xr = X + (size_t)(r0 + w * 16 + g * 4 + p) * KDIM + j0;
      float s = 0.f;
      #pragma unroll
      for (int cf = 0; cf < 4; ++cf)
        s += acc[cf][p] * xr[cf * 16 + lr];
      qacc[p] += s;
    }
  }

  // reduce across the 16 lr lanes of each k-group; one writer per row
  #pragma unroll
  for (int p = 0; p < 4; ++p) {
    float q = qacc[p];
    q += __shfl_xor(q, 1, 64);
    q += __shfl_xor(q, 2, 64);
    q += __shfl_xor(q, 4, 64);
    q += __shfl_xor(q, 8, 64);
    if (lr == 0) {
      const int row = w * 16 + g * 4 + p;
      qLds[row] = q;
      quad[r0 + row] = q;
    }
  }
  __syncthreads();
  // fused column stats over the (cache-hot) X panel
  {
    float s1a = 0.f, s2a = 0.f, s3a = 0.f, s1b = 0.f, s2b = 0.f, s3b = 0.f;
    for (int r = 0; r < BM; ++r) {
      const float q = qLds[r];
      const float* xp = X + (size_t)(r0 + r) * KDIM + tid;
      const float x0 = xp[0];
      const float x1 = xp[256];
      s1a += x0; s2a += x0 * x0; s3a += q * x0;
      s1b += x1; s2b += x1 * x1; s3b += q * x1;
    }
    atomicAdd(&colS1[tid], s1a); atomicAdd(&colS1[tid + 256], s1b);
    atomicAdd(&colS2[tid], s2a); atomicAdd(&colS2[tid + 256], s2b);
    atomicAdd(&colS3[tid], s3a); atomicAdd(&colS3[tid + 256], s3b);
  }
  if (tid < BM) {   // one full wave: reduce q, q^2 across 64 lanes
    double q = (double)qLds[tid];
    double q2 = q * q;
    #pragma unroll
    for (int m = 1; m < 64; m <<= 1) {
      q  += __shfl_xor(q,  m, 64);
      q2 += __shfl_xor(q2, m, 64);
    }
    if (tid == 0) { atomicAdd(&qsums[0], q); atomicAdd(&qsums[1], q2); }
  }
}

// ---------------- finalize per-feature mean / inv_std ----------------
__global__ void finalize_kernel(const float* __restrict__ colS1, const float* __restrict__ colS2,
                                const float* __restrict__ colS3, const double* __restrict__ qsums,
                                const float* __restrict__ C2, const float* __restrict__ C3,
                                float* __restrict__ mean, float* __restrict__ inv_std) {
  const int k = blockIdx.x * blockDim.x + threadIdx.x;
  if (k >= KDIM) return;
  const double invN = 1.0 / (double)NROWS;
  const double meanQ = qsums[0] * invN;
  const double varQ  = qsums[1] * invN - meanQ * meanQ;
  const float meanX = colS1[k] * (float)invN;
  const float varX  = colS2[k] * (float)invN - meanX * meanX;
  const float covQX = colS3[k] * (float)invN - (float)meanQ * meanX;
  const float c2 = C2[k];
  const float c3 = C3[0];
  const float m = (float)meanQ + c2 * meanX + c3;
  const float v = (float)varQ + c2 * c2 * varX + 2.0f * c2 * covQX;
  mean[k] = m;
  inv_std[k] = 1.0f / sqrtf(v + BN_EPS);
}

// ---------------- normalize + write ----------------
__global__ __launch_bounds__(256)
void normalize_kernel(const float* __restrict__ X, const float* __restrict__ quad,
                      const float* __restrict__ C2, const float* __restrict__ C3,
                      const float* __restrict__ mean, const float* __restrict__ inv_std,
                      float* __restrict__ out) {
  const int idx = blockIdx.x * blockDim.x + threadIdx.x;  // float4 index
  const int n = idx >> 7;
  const int j4 = idx & 127;
  const float q = quad[n];
  const float c3 = C3[0];
  const float4 x  = *(const float4*)&X[(size_t)idx * 4];
  const float4 c2 = *(const float4*)&C2[j4 * 4];
  const float4 m  = *(const float4*)&mean[j4 * 4];
  const float4 iv = *(const float4*)&inv_std[j4 * 4];
  float4 o;
  o.x = (q + c2.x * x.x + c3 - m.x) * iv.x;
  o.y = (q + c2.y * x.y + c3 - m.y) * iv.y;
  o.z = (q + c2.z * x.z + c3 - m.z) * iv.z;
  o.w = (q + c2.w * x.w + c3 - m.w) * iv.w;
  *(float4*)&out[(size_t)idx * 4] = o;
}

extern "C" void kernel_launch(void* const* d_in, const int* in_sizes, int n_in,
                              void* d_out, int out_size, void* d_ws, size_t ws_size,
                              hipStream_t stream) {
  const float* X  = (const float*)d_in[0];
  const float* C1 = (const float*)d_in[1];
  const float* C2 = (const float*)d_in[2];
  const float* C3 = (const float*)d_in[3];
  float* out = (float*)d_out;

  char* ws = (char*)d_ws;
  float*  quad    = (float*)ws;                                        // 256 KB
  float*  colS1   = (float*)(ws + (size_t)NROWS * 4);                  // K
  float*  colS2   = colS1 + KDIM;
  float*  colS3   = colS2 + KDIM;
  double* qsums   = (double*)(ws + (size_t)NROWS * 4 + 3 * KDIM * 4);  // 2 doubles
  float*  mean    = (float*)(ws + (size_t)NROWS * 4 + 3 * KDIM * 4 + 16);
  float*  inv_std = mean + KDIM;
  short8* c1tH    = (short8*)(ws + 276480);                            // 512 KB (16B aligned)

  hipMemsetAsync(colS1, 0, 3 * KDIM * 4 + 16, stream);

  prep_c1<<<128, 256, 0, stream>>>(C1, c1tH);
  quad_kernel<<<NROWS / BM, 256, 0, stream>>>(X, c1tH, quad,
                                              colS1, colS2, colS3, qsums);
  finalize_kernel<<<2, 256, 0, stream>>>(colS1, colS2, colS3, qsums, C2, C3, mean, inv_std);
  normalize_kernel<<<(NROWS * (KDIM / 4)) / 256, 256, 0, stream>>>(
      X, quad, C2, C3, mean, inv_std, out);
}